// Round 16
// baseline (113.095 us; speedup 1.0000x reference)
//
#include <hip/hip_runtime.h>

#define TPB   64     // one wave per block; everything wave-private (no s_barrier)
#define RPW   64     // rows per wave, one per lane
#define XDIM  99
#define NJ    26
#define OUTW  78
#define LSTR  49     // LDS row stride: banks (17l+c)%32 -> conflict-free scalar reads
#define SSTR  79     // flush scratch stride: banks (15r+c)%32 -> conflict-free

__device__ __forceinline__ float fast_rcp(float a)  { return __builtin_amdgcn_rcpf(a); }
__device__ __forceinline__ float fast_sqrt(float a) { return __builtin_amdgcn_sqrtf(a); }

__device__ __forceinline__ void rodrigues(float ax, float ay, float az, float* R) {
    const float EPS = 1.1920928955078125e-07f;   // np.finfo(np.float32).eps
    float t = fast_sqrt(ax*ax + ay*ay + az*az);
    float inv = fast_rcp(t + EPS);
    float r0 = ax*inv, r1 = ay*inv, r2 = az*inv;
    float s, c;
    __sincosf(t, &s, &c);
    float omc = 1.0f - c;
    float r00 = r0*r0, r11 = r1*r1, r22 = r2*r2;
    float r01 = r0*r1, r02 = r0*r2, r12 = r1*r2;
    R[0] = 1.0f - omc*(r11 + r22);
    R[1] = -s*r2 + omc*r01;
    R[2] =  s*r1 + omc*r02;
    R[3] =  s*r2 + omc*r01;
    R[4] = 1.0f - omc*(r00 + r22);
    R[5] = -s*r0 + omc*r12;
    R[6] = -s*r1 + omc*r02;
    R[7] =  s*r0 + omc*r12;
    R[8] = 1.0f - omc*(r00 + r11);
}

// (64,3): VGPR cap ~170 (R13 live set was 84; pp+ang+temps fit). LDS 12544B
// caps residency at ~13 blocks/CU = 13 waves — the occupancy binder.
__global__ __launch_bounds__(TPB, 3) void skel_fk(const float* __restrict__ x,
                                                  const float* __restrict__ off,
                                                  float* __restrict__ out) {
    __shared__ float buf[RPW * LSTR];            // 12544 B
    const int l = threadIdx.x;
    const int row0 = blockIdx.x * RPW;
    const float* xb = x + (long long)row0 * XDIM;

    // slot tables (slot 0 = hip, slots 1..25 follow ORDER)
    constexpr int OFF_IDX[NJ] = {0,1,2,3,4,6,7,8,9,11,12,13,14,15,16,17,18,19,20,22,24,25,26,27,28,30};
    constexpr int PAR[NJ]     = {-1,0,1,2,3,0,5,6,7,0,9,10,11,12,10,14,15,16,17,17,10,20,21,22,23,23};

    // ---- stage chunk A: buf[49r + c] = x[99r + c], c in [0,48] (c=48 pad=junk).
    //      width-4 global_load_lds: LDS dest linear (base+lane*4), global src
    //      per-lane (m173). Coalesced: 64 consecutive f -> ~1.3 rows, 4-5 lines. ----
    #pragma unroll
    for (int j = 0; j < 49; ++j) {
        const int f = l + 64 * j;
        const int r = f / LSTR;                  // const divisor -> magic mul
        const int c = f - LSTR * r;
        __builtin_amdgcn_global_load_lds(
            (const __attribute__((address_space(1))) unsigned int*)(xb + 99*r + c),
            (__attribute__((address_space(3))) unsigned int*)(buf + 64*j),
            4, 0, 0);
    }
    asm volatile("s_waitcnt vmcnt(0)" ::: "memory");   // wave-local drain, no barrier
    __builtin_amdgcn_sched_barrier(0);

    const float* row = &buf[l * LSTR];           // this lane's 48-float chunk view
    float ang[NJ][9];                            // compile-time indices -> registers
    float pp[NJ][3];                             // live until flush

    // ---- compute slots 0..12 from chunk A (cols 0..47) ----
    {
        float R[9];
        rodrigues(row[3], row[4], row[5], R);
        #pragma unroll
        for (int q = 0; q < 9; ++q) ang[0][q] = R[q];
        pp[0][0] = off[0] + row[0];
        pp[0][1] = off[1] + row[1];
        pp[0][2] = off[2] + row[2];
    }
    #pragma unroll
    for (int s = 1; s <= 12; ++s) {
        const int i  = OFF_IDX[s];
        const int pa = PAR[s];
        const int col = 3*i + 3;                 // in [6,47]
        float L[9];
        rodrigues(row[col], row[col+1], row[col+2], L);
        const float o0 = off[3*i], o1 = off[3*i+1], o2 = off[3*i+2];
        #pragma unroll
        for (int c = 0; c < 3; ++c)
            pp[s][c] = o0*ang[pa][c] + o1*ang[pa][3+c] + o2*ang[pa][6+c] + pp[pa][c];
        #pragma unroll
        for (int j = 0; j < 3; ++j)
            #pragma unroll
            for (int kk = 0; kk < 3; ++kk)
                ang[s][3*j+kk] = L[3*j+0]*ang[pa][0+kk]
                               + L[3*j+1]*ang[pa][3+kk]
                               + L[3*j+2]*ang[pa][6+kk];
    }
    __builtin_amdgcn_sched_barrier(0);           // pin chunk-A reads before B's DMA

    // ---- stage chunk B: buf[49r + c] = x[99r + 48 + c] (overwrites slab;
    //      all chunk-A reads consumed above) ----
    #pragma unroll
    for (int j = 0; j < 49; ++j) {
        const int f = l + 64 * j;
        const int r = f / LSTR;
        const int c = f - LSTR * r;
        __builtin_amdgcn_global_load_lds(
            (const __attribute__((address_space(1))) unsigned int*)(xb + 99*r + 48 + c),
            (__attribute__((address_space(3))) unsigned int*)(buf + 64*j),
            4, 0, 0);
    }
    asm volatile("s_waitcnt vmcnt(0)" ::: "memory");
    __builtin_amdgcn_sched_barrier(0);

    // ---- compute slots 13..25 from chunk B (cols 0..45) ----
    #pragma unroll
    for (int s = 13; s < NJ; ++s) {
        const int i  = OFF_IDX[s];
        const int pa = PAR[s];
        const int col = 3*i + 3 - 48;
        float L[9];
        rodrigues(row[col], row[col+1], row[col+2], L);
        const float o0 = off[3*i], o1 = off[3*i+1], o2 = off[3*i+2];
        #pragma unroll
        for (int c = 0; c < 3; ++c)
            pp[s][c] = o0*ang[pa][c] + o1*ang[pa][3+c] + o2*ang[pa][6+c] + pp[pa][c];
        #pragma unroll
        for (int j = 0; j < 3; ++j)
            #pragma unroll
            for (int kk = 0; kk < 3; ++kk)
                ang[s][3*j+kk] = L[3*j+0]*ang[pa][0+kk]
                               + L[3*j+1]*ang[pa][3+kk]
                               + L[3*j+2]*ang[pa][6+kk];
    }
    __builtin_amdgcn_sched_barrier(0);           // slab now dead -> scratch reuse

    // ---- flush: 2 groups of 32 rows via in-slab scratch (stride 79).
    //      Wave-local ordering only (lgkmcnt); full 64B lines, single touch. ----
    float* ob = out + (long long)row0 * OUTW;
    #pragma unroll
    for (int g2 = 0; g2 < 2; ++g2) {
        __builtin_amdgcn_sched_barrier(0);       // keep g1 writes after g0 reads
        if ((l >> 5) == g2) {
            float* srow = &buf[(l & 31) * SSTR]; // banks 15*(l&31)+c: conflict-free
            #pragma unroll
            for (int s = 0; s < NJ; ++s) {
                srow[3*s+0] = pp[s][0];
                srow[3*s+1] = pp[s][1];
                srow[3*s+2] = pp[s][2];
            }
        }
        asm volatile("s_waitcnt lgkmcnt(0)" ::: "memory");  // writes visible wave-wide
        __builtin_amdgcn_sched_barrier(0);
        #pragma unroll
        for (int j = 0; j < 39; ++j) {           // 39*64 = 2496 = 32*78 exact
            const int m = l + 64 * j;
            const int r = m / OUTW;              // const divisor -> magic mul
            const int c = m - OUTW * r;
            ob[g2 * (32 * OUTW) + m] = buf[r * SSTR + c];
        }
    }
}

extern "C" void kernel_launch(void* const* d_in, const int* in_sizes, int n_in,
                              void* d_out, int out_size, void* d_ws, size_t ws_size,
                              hipStream_t stream) {
    const float* x   = (const float*)d_in[0];
    const float* off = (const float*)d_in[1];
    float* out = (float*)d_out;
    const int B = in_sizes[0] / XDIM;      // 262144
    const int grid = B / RPW;              // 4096
    skel_fk<<<grid, TPB, 0, stream>>>(x, off, out);
}

// Round 17
// 39.785 us; speedup vs baseline: 2.8427x; 2.8427x over previous
//
#include <hip/hip_runtime.h>

#define TPB   64     // one wave per block; fully wave-private
#define RPW   64     // rows per block, one per lane
#define XDIM  99
#define NJ    26
#define OUTW  78

__device__ __forceinline__ float fast_rcp(float a)  { return __builtin_amdgcn_rcpf(a); }
__device__ __forceinline__ float fast_sqrt(float a) { return __builtin_amdgcn_sqrtf(a); }

__device__ __forceinline__ void rodrigues(float ax, float ay, float az, float* R) {
    const float EPS = 1.1920928955078125e-07f;   // np.finfo(np.float32).eps
    float t = fast_sqrt(ax*ax + ay*ay + az*az);
    float inv = fast_rcp(t + EPS);
    float r0 = ax*inv, r1 = ay*inv, r2 = az*inv;
    float s, c;
    __sincosf(t, &s, &c);
    float omc = 1.0f - c;
    float r00 = r0*r0, r11 = r1*r1, r22 = r2*r2;
    float r01 = r0*r1, r02 = r0*r2, r12 = r1*r2;
    R[0] = 1.0f - omc*(r11 + r22);
    R[1] = -s*r2 + omc*r01;
    R[2] =  s*r1 + omc*r02;
    R[3] =  s*r2 + omc*r01;
    R[4] = 1.0f - omc*(r00 + r22);
    R[5] = -s*r0 + omc*r12;
    R[6] = -s*r1 + omc*r02;
    R[7] =  s*r0 + omc*r12;
    R[8] = 1.0f - omc*(r00 + r11);
}

// (64,4): VGPR cap 128 (R13's identical live set measured 84). LDS 25.3KB ->
// 6 blocks/CU; blocks are independent single waves (no cross-wave barriers).
__global__ __launch_bounds__(TPB, 4) void skel_fk(const float* __restrict__ x,
                                                  const float* __restrict__ off,
                                                  float* __restrict__ out) {
    __shared__ __align__(16) float buf[RPW * XDIM];   // 25344 B slab
    const int l = threadIdx.x;
    const int row0 = blockIdx.x * RPW;
    const float* gsrc = x + (long long)row0 * XDIM;

    // ---- linear DMA stage (R10's proven pattern): 24 x 16B-wide (1KB/instr)
    //      + 3 x 4B-wide (256B/instr) covers all 25344 B. LDS dest uniform
    //      base + lane*width; global src the SAME linear layout. ----
    #pragma unroll
    for (int j = 0; j < 24; ++j) {
        __builtin_amdgcn_global_load_lds(
            (const __attribute__((address_space(1))) unsigned int*)(gsrc + 256*j + 4*l),
            (__attribute__((address_space(3))) unsigned int*)(buf + 256*j),
            16, 0, 0);
    }
    #pragma unroll
    for (int kk = 0; kk < 3; ++kk) {
        __builtin_amdgcn_global_load_lds(
            (const __attribute__((address_space(1))) unsigned int*)(gsrc + 6144 + 64*kk + l),
            (__attribute__((address_space(3))) unsigned int*)(buf + 6144 + 64*kk),
            4, 0, 0);
    }
    __syncthreads();                             // 1-wave: vmcnt drain, no convoy

    const float* row = &buf[l * XDIM];           // stride 99 (odd) -> conflict-free

    // slot tables (slot 0 = hip, slots 1..25 follow ORDER)
    constexpr int OFF_IDX[NJ] = {0,1,2,3,4,6,7,8,9,11,12,13,14,15,16,17,18,19,20,22,24,25,26,27,28,30};
    constexpr int PAR[NJ]     = {-1,0,1,2,3,0,5,6,7,0,9,10,11,12,10,14,15,16,17,17,10,20,21,22,23,23};

    float ang[NJ][9];   // compile-time indices -> SSA registers
    float pp[NJ][3];    // live until flush (R13-proven 84-reg live set)

    {
        float R[9];
        rodrigues(row[3], row[4], row[5], R);
        #pragma unroll
        for (int q = 0; q < 9; ++q) ang[0][q] = R[q];
        pp[0][0] = off[0] + row[0];
        pp[0][1] = off[1] + row[1];
        pp[0][2] = off[2] + row[2];
    }

    #pragma unroll
    for (int s = 1; s < NJ; ++s) {
        const int i  = OFF_IDX[s];
        const int pa = PAR[s];
        float L[9];
        rodrigues(row[3*i+3], row[3*i+4], row[3*i+5], L);   // LDS, conflict-free
        const float o0 = off[3*i], o1 = off[3*i+1], o2 = off[3*i+2];  // uniform
        #pragma unroll
        for (int c = 0; c < 3; ++c)
            pp[s][c] = o0*ang[pa][c] + o1*ang[pa][3+c] + o2*ang[pa][6+c] + pp[pa][c];
        #pragma unroll
        for (int j = 0; j < 3; ++j)
            #pragma unroll
            for (int kk = 0; kk < 3; ++kk)
                ang[s][3*j+kk] = L[3*j+0]*ang[pa][0+kk]
                               + L[3*j+1]*ang[pa][3+kk]
                               + L[3*j+2]*ang[pa][6+kk];
    }
    __syncthreads();                             // all input reads done (wave-local)

    // ---- pack pos into the dead slab at stride 78: lane l -> floats [78l,78l+78).
    //      float2 writes, 8B-aligned (312l + 8j). Makes flush a LINEAR copy. ----
    {
        float2* wr2 = reinterpret_cast<float2*>(buf) + 39 * l;
        #pragma unroll
        for (int j = 0; j < 39; ++j) {
            float2 v;
            v.x = pp[(2*j)   / 3][(2*j)   % 3];  // compile-time indices
            v.y = pp[(2*j+1) / 3][(2*j+1) % 3];
            wr2[j] = v;
        }
    }
    __syncthreads();                             // packed data visible wave-wide

    // ---- flush: pure linear copy, full 64B lines, single touch.
    //      out block base = row0*312 B, multiple of 16 -> float4 aligned. ----
    {
        float4* ob4 = reinterpret_cast<float4*>(out + (long long)row0 * OUTW);
        const float4* b4 = reinterpret_cast<const float4*>(buf);
        #pragma unroll
        for (int j = 0; j < 19; ++j)             // 19*64 = 1216 float4 = 4864 floats
            ob4[l + 64*j] = b4[l + 64*j];
        float2* ob2 = reinterpret_cast<float2*>(out + (long long)row0 * OUTW);
        const float2* b2 = reinterpret_cast<const float2*>(buf);
        ob2[2432 + l] = b2[2432 + l];            // tail: floats [4864, 4992)
    }
}

extern "C" void kernel_launch(void* const* d_in, const int* in_sizes, int n_in,
                              void* d_out, int out_size, void* d_ws, size_t ws_size,
                              hipStream_t stream) {
    const float* x   = (const float*)d_in[0];
    const float* off = (const float*)d_in[1];
    float* out = (float*)d_out;
    const int B = in_sizes[0] / XDIM;      // 262144
    const int grid = B / RPW;              // 4096
    skel_fk<<<grid, TPB, 0, stream>>>(x, off, out);
}